// Round 1
// baseline (251.142 us; speedup 1.0000x reference)
//
#include <hip/hip_runtime.h>

// Problem constants (from reference): N=4, C=320, H=W=D=16 -> L=4096, POS_RATIO=0.5
#define LVOX   4096
#define NCH    320
#define NCOMBO 8        // 4 batches x 2 branches (normal, batch-flipped q)
#define MAXCAP 131072   // pairs per combo (worst-case analysis ~80K)
#define CHUNKS 4        // pair-list chunks per (combo, channel) in dot kernel

struct Geo {
    float qs0, qs1, qs2, qo0, qo1, qo2;   // q-side bin size / origin
    float ks0, ks1, ks2, ko0, ko1, ko2;   // k-side bin size / origin
    float ik0, ik1, ik2;                  // 1 / k bin size
    float T;                              // 0.5 * max(diag_q[n], diag_k[n])
};

// n = batch index (k side, and diag indexing); qb = q-side batch (3-n for flipped branch).
// NOTE: max_diag is computed from the UNFLIPPED diag_q[n] even in the flipped branch
// (reference computes max_diag before masked_loss is applied to flipped inputs).
__device__ __forceinline__ Geo make_geo(const float* __restrict__ cq,
                                        const float* __restrict__ ck,
                                        int n, int qb) {
    Geo g;
    const float* qc = cq + qb * 6;   // q centers use qb
    const float* qn = cq + n * 6;    // diag_q uses n
    const float* kc = ck + n * 6;
    g.qs0 = (qc[3] - qc[0]) * (1.f / 16.f); g.qo0 = qc[0];
    g.qs1 = (qc[4] - qc[1]) * (1.f / 16.f); g.qo1 = qc[1];
    g.qs2 = (qc[5] - qc[2]) * (1.f / 16.f); g.qo2 = qc[2];
    g.ks0 = (kc[3] - kc[0]) * (1.f / 16.f); g.ko0 = kc[0];
    g.ks1 = (kc[4] - kc[1]) * (1.f / 16.f); g.ko1 = kc[1];
    g.ks2 = (kc[5] - kc[2]) * (1.f / 16.f); g.ko2 = kc[2];
    g.ik0 = 1.f / g.ks0; g.ik1 = 1.f / g.ks1; g.ik2 = 1.f / g.ks2;
    float b0 = (qn[3] - qn[0]) * (1.f / 16.f);
    float b1 = (qn[4] - qn[1]) * (1.f / 16.f);
    float b2 = (qn[5] - qn[2]) * (1.f / 16.f);
    float dq = sqrtf(b0 * b0 + b1 * b1 + b2 * b2);
    float dk = sqrtf(g.ks0 * g.ks0 + g.ks1 * g.ks1 + g.ks2 * g.ks2);
    g.T = 0.5f * fmaxf(dq, dk);
    return g;
}

// candidate m-range on one axis: k-center within [c-T, c+T]; widened by 1 for fp32 safety
__device__ __forceinline__ void axrange(float c, float ko, float ik, float T,
                                        int& m0, int& m1) {
    float lo = (c - T - ko) * ik - 0.5f;
    float hi = (c + T - ko) * ik - 0.5f;
    m0 = max((int)ceilf(lo) - 1, 0);
    m1 = min((int)floorf(hi) + 1, 15);
}

// ws layout: [float S[8]][unsigned pcnt[8]][unsigned pairs[NCOMBO*cap]]
__global__ void enum_pairs(const float* __restrict__ coord_q,
                           const float* __restrict__ coord_k,
                           unsigned* __restrict__ pcnt,
                           unsigned* __restrict__ pairs, int cap) {
    int gid = blockIdx.x * 256 + threadIdx.x;   // 8*4096 threads
    int j = gid >> 12;                          // combo
    int l = gid & 4095;
    int n = j & 3;
    int qb = (j & 4) ? (3 - n) : n;
    Geo g = make_geo(coord_q, coord_k, n, qb);

    int ix = l >> 8, iy = (l >> 4) & 15, iz = l & 15;
    float cx = (ix + 0.5f) * g.qs0 + g.qo0;
    float cy = (iy + 0.5f) * g.qs1 + g.qo1;
    float cz = (iz + 0.5f) * g.qs2 + g.qo2;
    int x0, x1, y0, y1, z0, z1;
    axrange(cx, g.ko0, g.ik0, g.T, x0, x1);
    axrange(cy, g.ko1, g.ik1, g.T, y0, y1);
    axrange(cz, g.ko2, g.ik2, g.T, z0, z1);

    // pass 1: count hits
    int nh = 0;
    for (int x = x0; x <= x1; ++x) {
        float dx = cx - ((x + 0.5f) * g.ks0 + g.ko0);
        float dx2 = dx * dx;
        for (int y = y0; y <= y1; ++y) {
            float dy = cy - ((y + 0.5f) * g.ks1 + g.ko1);
            float dxy = dx2 + dy * dy;
            for (int z = z0; z <= z1; ++z) {
                float dz = cz - ((z + 0.5f) * g.ks2 + g.ko2);
                if (sqrtf(dxy + dz * dz) < g.T) nh++;
            }
        }
    }

    // wave-aggregated reservation (all lanes of a wave share the same combo j)
    int lane = threadIdx.x & 63;
    int incl = nh;
#pragma unroll
    for (int off = 1; off < 64; off <<= 1) {
        int t = __shfl_up(incl, off, 64);
        if (lane >= off) incl += t;
    }
    int total = __shfl(incl, 63, 64);
    int base = 0;
    if (lane == 63) base = (int)atomicAdd(&pcnt[j], (unsigned)total);
    base = __shfl(base, 63, 64);
    int w = base + incl - nh;

    // pass 2: write pairs
    unsigned* out = pairs + (size_t)j * (size_t)cap;
    for (int x = x0; x <= x1; ++x) {
        float dx = cx - ((x + 0.5f) * g.ks0 + g.ko0);
        float dx2 = dx * dx;
        for (int y = y0; y <= y1; ++y) {
            float dy = cy - ((y + 0.5f) * g.ks1 + g.ko1);
            float dxy = dx2 + dy * dy;
            for (int z = z0; z <= z1; ++z) {
                float dz = cz - ((z + 0.5f) * g.ks2 + g.ko2);
                if (sqrtf(dxy + dz * dz) < g.T) {
                    if (w < cap)
                        out[w] = ((unsigned)l << 12) | (unsigned)((x << 8) | (y << 4) | z);
                    w++;
                }
            }
        }
    }
}

// one wave per (combo, channel, chunk): gather q[qb,c,l]*k[n,c,m] over the pair list.
// Each wave touches only two 16KB rows -> L1-resident gathers.
__global__ void dot_pairs(const float* __restrict__ q, const float* __restrict__ k,
                          const unsigned* __restrict__ pcnt,
                          const unsigned* __restrict__ pairs, int cap,
                          float* __restrict__ S) {
    int wid = blockIdx.x * (blockDim.x >> 6) + (threadIdx.x >> 6);
    int lane = threadIdx.x & 63;
    int chunk = wid & (CHUNKS - 1);
    int rest = wid >> 2;           // CHUNKS == 4
    int c = rest % NCH;
    int j = rest / NCH;
    if (j >= NCOMBO) return;
    int n = j & 3;
    int qb = (j & 4) ? (3 - n) : n;

    const float* qrow = q + ((size_t)(qb * NCH + c)) * LVOX;
    const float* krow = k + ((size_t)(n * NCH + c)) * LVOX;
    const unsigned* pl = pairs + (size_t)j * (size_t)cap;
    unsigned cnt = pcnt[j];
    if (cnt > (unsigned)cap) cnt = (unsigned)cap;

    float acc = 0.f;
    for (unsigned p = (unsigned)(chunk * 64 + lane); p < cnt; p += 64u * CHUNKS) {
        unsigned pr = pl[p];
        int l = (int)(pr >> 12);
        int m = (int)(pr & 4095u);
        acc += qrow[l] * krow[m];
    }
#pragma unroll
    for (int off = 32; off; off >>= 1) acc += __shfl_down(acc, off, 64);
    if (lane == 0) atomicAdd(&S[j], acc);
}

__global__ void finalize(const float* __restrict__ S,
                         const unsigned* __restrict__ pcnt,
                         float* __restrict__ out) {
    if (threadIdx.x == 0) {
        float t = 0.f;
#pragma unroll
        for (int j = 0; j < NCOMBO; ++j)
            t += S[j] / ((float)pcnt[j] + 1e-6f);
        out[0] = -0.5f * t;   // -2*mean(4 batches) per branch, 2 branches
    }
}

extern "C" void kernel_launch(void* const* d_in, const int* in_sizes, int n_in,
                              void* d_out, int out_size, void* d_ws, size_t ws_size,
                              hipStream_t stream) {
    const float* q       = (const float*)d_in[0];
    const float* k       = (const float*)d_in[1];
    const float* coord_q = (const float*)d_in[2];
    const float* coord_k = (const float*)d_in[3];
    float* out = (float*)d_out;

    float*    S     = (float*)d_ws;              // 8 floats
    unsigned* pcnt  = (unsigned*)d_ws + 8;       // 8 uints
    unsigned* pairs = (unsigned*)d_ws + 16;

    size_t avail = (ws_size > 64) ? (ws_size / 4 - 16) / NCOMBO : 1;
    int cap = (int)((avail < (size_t)MAXCAP) ? avail : (size_t)MAXCAP);
    if (cap < 1) cap = 1;

    hipMemsetAsync(d_ws, 0, 64, stream);
    enum_pairs<<<(NCOMBO * LVOX) / 256, 256, 0, stream>>>(coord_q, coord_k, pcnt, pairs, cap);
    dot_pairs<<<(NCOMBO * NCH * CHUNKS) / 4, 256, 0, stream>>>(q, k, pcnt, pairs, cap, S);
    finalize<<<1, 64, 0, stream>>>(S, pcnt, out);
}